// Round 16
// baseline (82.317 us; speedup 1.0000x reference)
//
#include <hip/hip_runtime.h>
#include <cstdint>

// ---------------------------------------------------------------------------
// MoDBlock: B=2, T=2048, C=512, E=2, NH=8, hs=64, k=1024 (hardcoded).
// Output: out [B,T,C] f32 (2097152) + loss (1).
// R13 structure + cross-tile K-prefetch in k_attn (single isolated diff).
// ---------------------------------------------------------------------------

#define DI __device__ __forceinline__

typedef __bf16 bf16x8 __attribute__((ext_vector_type(8)));
typedef float  f32x4  __attribute__((ext_vector_type(4)));
typedef short  s16x4  __attribute__((ext_vector_type(4)));
typedef short  s16x8  __attribute__((ext_vector_type(8)));

DI uint16_t f2bf(float f) {
    union { float f; uint32_t u; } v; v.f = f;
    uint32_t u = v.u;
    uint32_t r = (u + 0x7FFFu + ((u >> 16) & 1u)) >> 16;   // RNE; finite inputs only
    return (uint16_t)r;
}

DI f32x4 mfma16(bf16x8 a, bf16x8 b, f32x4 c) {
    return __builtin_amdgcn_mfma_f32_16x16x32_bf16(a, b, c, 0, 0, 0);
}
DI f32x4 mfma_k16(s16x4 a, s16x4 b, f32x4 c) {
    return __builtin_amdgcn_mfma_f32_16x16x16bf16_1k(a, b, c, 0, 0, 0);
}
DI void gload16(const void* g, void* l) {       // async 16B/lane global->LDS
    __builtin_amdgcn_global_load_lds(
        (const __attribute__((address_space(1))) uint32_t*)g,
        (__attribute__((address_space(3))) uint32_t*)l, 16, 0, 0);
}

// ---- workspace layout (bytes) ----
constexpr size_t OFF_LOGITS = 0;                                // 4096 f32
constexpr size_t OFF_PL     = OFF_LOGITS + 4096 * 4;            // 4096 f32
constexpr size_t OFF_MASK   = OFF_PL     + 4096 * 4;            // 4096 int
constexpr size_t OFF_POSMAP = OFF_MASK   + 4096 * 4;            // 4096 int
constexpr size_t OFF_IDX    = OFF_POSMAP + 4096 * 4;            // 2048 int
constexpr size_t OFF_WSEL   = OFF_IDX    + 2048 * 4;            // 2048 f32
constexpr size_t OFF_GATE   = OFF_WSEL   + 2048 * 4;            // 2048*2 f32
constexpr size_t OFF_SELBF  = OFF_GATE   + 4096 * 4;            // 2048*512 bf16
constexpr size_t OFF_WQKVT  = OFF_SELBF  + 2048 * 512 * 2;      // [2048][512] bf16
constexpr size_t OFF_WPROJT = OFF_WQKVT  + 2048 * 512 * 2;      // [512][512] bf16
constexpr size_t OFF_QKVRAW = OFF_WPROJT + 512 * 512 * 2;       // 2048*2048 f32
constexpr size_t OFF_QH     = OFF_QKVRAW + (size_t)2048 * 2048 * 4; // [B,E,NH,k,64] bf16
constexpr size_t OFF_KH     = OFF_QH     + (size_t)2097152 * 2;     // [B,NH,k,64] bf16 (pre-scaled 1/8)
constexpr size_t OFF_VT     = OFF_KH     + (size_t)1048576 * 2;     // [B,NH,64,k] bf16 (kv-swizzled)
constexpr size_t OFF_YBF    = OFF_VT     + (size_t)1048576 * 2;     // [B,E,k,512] bf16

// ---------------------------------------------------------------------------
// 1. prep: weight transpose+cast (0..319) + router/predictor logits (320..1343).
__global__ __launch_bounds__(256) void k_prep(const float* __restrict__ Wq,
                                              const float* __restrict__ Wkv,
                                              const float* __restrict__ Wp,
                                              uint16_t* __restrict__ Wqkvt,
                                              uint16_t* __restrict__ Wprojt,
                                              const float* __restrict__ x,
                                              const float* __restrict__ wr,
                                              const float* __restrict__ wp,
                                              float* __restrict__ logits,
                                              float* __restrict__ pl) {
    __shared__ float tile[64][65];
    int blk = blockIdx.x, tid = threadIdx.x;
    if (blk >= 320) {                  // router + predictor logits
        int rblk = blk - 320;
        int wid  = rblk * 4 + (tid >> 6);
        int lane = tid & 63;
        const float* xr = x + (size_t)wid * 512;
        double s = 0.0; float sp = 0.f;
#pragma unroll
        for (int j = 0; j < 8; j++) {
            int c = lane + 64 * j;
            float xv = xr[c];
            s  += (double)xv * (double)wr[c];
            sp += xv * wp[c];
        }
        for (int m = 1; m < 64; m <<= 1) { s += __shfl_xor(s, m); sp += __shfl_xor(sp, m); }
        if (lane == 0) { logits[wid] = (float)s; pl[wid] = sp; }
        return;
    }
    const float* src; uint16_t* dst; int n0, c0, ldn;
    if (blk < 256) {                   // qkv: dest [2048][512]
        int tn = blk & 31, tc = blk >> 5;
        n0 = tn * 64; c0 = tc * 64; ldn = 1024;
        if (n0 < 1024) { src = Wq; } else { src = Wkv; n0 -= 1024; }
        dst = Wqkvt + (size_t)(tn * 64) * 512 + c0;
    } else {                           // proj: dest [512][512]
        int j = blk - 256; int tn = j & 7, tc = j >> 3;
        n0 = tn * 64; c0 = tc * 64; ldn = 512;
        src = Wp; dst = Wprojt + (size_t)n0 * 512 + c0;
    }
    int nl = tid & 63, cb = tid >> 6;
#pragma unroll
    for (int p = 0; p < 16; p++) {
        int cl_ = p * 4 + cb;
        tile[cl_][nl] = src[(size_t)(c0 + cl_) * ldn + n0 + nl];
    }
    __syncthreads();
    int cp = tid & 31, nb = tid >> 5;
#pragma unroll
    for (int p = 0; p < 8; p++) {
        int nl2 = p * 8 + nb;
        uint32_t pk = (uint32_t)f2bf(tile[cp * 2][nl2]) |
                      ((uint32_t)f2bf(tile[cp * 2 + 1][nl2]) << 16);
        *(uint32_t*)&dst[(size_t)nl2 * 512 + cp * 2] = pk;
    }
}

// 2. rank: count of strictly-greater (or equal with smaller index) -> mask
__global__ void k_rank(const float* __restrict__ logits, int* __restrict__ mask) {
    int wid  = (blockIdx.x * blockDim.x + threadIdx.x) >> 6;
    int lane = threadIdx.x & 63;
    if (wid >= 4096) return;
    int b = wid >> 11, t = wid & 2047;
    const float* lb = logits + b * 2048;
    float v = lb[t];
    int cnt = 0;
    for (int j = 0; j < 32; j++) {
        int tp = lane + 64 * j;
        float lv = lb[tp];
        bool pred = (lv > v) || (lv == v && tp < t);
        cnt += __popcll(__ballot(pred));
    }
    if (lane == 0) mask[wid] = (cnt < 1024) ? 1 : 0;
}

// 3. wave-scan selection: idx (temporal order), wsel, posmap. 1 block/batch.
__global__ void k_select(const float* __restrict__ logits, const int* __restrict__ mask,
                         int* __restrict__ idx, float* __restrict__ wsel,
                         int* __restrict__ posmap) {
    __shared__ int wsum[16], woff[16];
    int b = blockIdx.x, tid = threadIdx.x, lane = tid & 63, w = tid >> 6;
    int t0 = tid * 2, t1 = tid * 2 + 1;
    int m0 = mask[b * 2048 + t0], m1 = mask[b * 2048 + t1];
    int s = m0 + m1;
    int sc = s;
    for (int off = 1; off < 64; off <<= 1) {
        int v = __shfl_up(sc, off);
        if (lane >= off) sc += v;
    }
    if (lane == 63) wsum[w] = sc;
    __syncthreads();
    if (tid < 16) {
        int acc = 0;
        for (int j = 0; j < tid; j++) acc += wsum[j];
        woff[tid] = acc;
    }
    __syncthreads();
    int excl = woff[w] + sc - s;
    int p0 = excl, p1 = excl + m0;
    if (m0) {
        idx[b * 1024 + p0] = t0;
        float v = logits[b * 2048 + t0];
        wsel[b * 1024 + p0] = 1.f / (1.f + __expf(-v));
    }
    posmap[b * 2048 + t0] = m0 ? p0 : -1;
    if (m1) {
        idx[b * 1024 + p1] = t1;
        float v = logits[b * 2048 + t1];
        wsel[b * 1024 + p1] = 1.f / (1.f + __expf(-v));
    }
    posmap[b * 2048 + t1] = m1 ? p1 : -1;
}

// 4. gather selected rows -> bf16 + gate (blk<2048); copy UNSELECTED rows x->out
//    (blk in [2048,4096): 2 rows/block over ALL 4096 rows, posmap<0 only).
__global__ void k_gather_gate(const float* __restrict__ x, const int* __restrict__ idx,
                              const float* __restrict__ Wg, const int* __restrict__ posmap,
                              uint16_t* __restrict__ selbf, float* __restrict__ gate,
                              float* __restrict__ out) {
    __shared__ float red0[4], red1[4];
    int blk = blockIdx.x;
    int tid = threadIdx.x, lane = tid & 63, w = tid >> 6;
    if (blk >= 2048) {                 // copy phase: rows 0..4095
        int row = (blk - 2048) * 2 + (tid >> 7);   // 2 rows/block, 2048 blocks
        int ci = tid & 127;
        if (posmap[row] < 0) {
            const float4* xr = (const float4*)(x + (size_t)row * 512);
            float4* orow = (float4*)(out + (size_t)row * 512);
            orow[ci] = xr[ci];
        }
        return;
    }
    int b = blk >> 10;
    int t = idx[blk];
    const float* xr = x + ((size_t)b * 2048 + t) * 512;
    int c = tid * 2;
    float v0 = xr[c], v1 = xr[c + 1];
    uint32_t pk = (uint32_t)f2bf(v0) | ((uint32_t)f2bf(v1) << 16);
    ((uint32_t*)(selbf + (size_t)blk * 512))[tid] = pk;
    float g0 = v0 * Wg[c * 2]     + v1 * Wg[(c + 1) * 2];
    float g1 = v0 * Wg[c * 2 + 1] + v1 * Wg[(c + 1) * 2 + 1];
    for (int m = 1; m < 64; m <<= 1) { g0 += __shfl_xor(g0, m); g1 += __shfl_xor(g1, m); }
    if (lane == 0) { red0[w] = g0; red1[w] = g1; }
    __syncthreads();
    if (tid == 0) {
        float a = red0[0] + red0[1] + red0[2] + red0[3];
        float bq = red1[0] + red1[1] + red1[2] + red1[3];
        float mx = fmaxf(a, bq);
        float ea = __expf(a - mx), eb = __expf(bq - mx), s = ea + eb;
        gate[blk * 2] = ea / s; gate[blk * 2 + 1] = eb / s;
    }
}

// 5. bf16 MFMA GEMM, m97-style async staging: C[M,N] f32 = A[M,K] @ Bt[N,K]^T.
__global__ __launch_bounds__(256) void k_gemm(const uint16_t* __restrict__ A,
                                              const uint16_t* __restrict__ Bt,
                                              float* __restrict__ Cc,
                                              int M, int N, int Kd) {
    __shared__ uint16_t As[128 * 32];   // 8 KB
    __shared__ uint16_t Bs[64 * 32];    // 4 KB
    int tid = threadIdx.x, lane = tid & 63, w = tid >> 6;
    int m0 = blockIdx.x * 128, n0 = blockIdx.y * 64;
    int wr = (w >> 1) * 64, wc = (w & 1) * 32;
    int cl = lane & 15, gp = lane >> 4;
    f32x4 acc[4][2];
#pragma unroll
    for (int mt = 0; mt < 4; mt++)
#pragma unroll
        for (int nt = 0; nt < 2; nt++)
#pragma unroll
            for (int r = 0; r < 4; r++) acc[mt][nt][r] = 0.f;
    int srow = lane >> 2, skc = (lane & 3) * 8;
    for (int ks = 0; ks < Kd; ks += 32) {
        __syncthreads();
        const uint16_t* ga0 = A + (size_t)(m0 + w * 32 + srow) * Kd + ks + skc;
        gload16(ga0, &As[(w * 32) * 32]);
        gload16(ga0 + (size_t)16 * Kd, &As[(w * 32 + 16) * 32]);
        const uint16_t* gb = Bt + (size_t)(n0 + w * 16 + srow) * Kd + ks + skc;
        gload16(gb, &Bs[(w * 16) * 32]);
        __syncthreads();
        bf16x8 af[4], bfr[2];
#pragma unroll
        for (int t = 0; t < 4; t++)
            af[t] = *(const bf16x8*)&As[(wr + t * 16 + cl) * 32 + gp * 8];
#pragma unroll
        for (int t = 0; t < 2; t++)
            bfr[t] = *(const bf16x8*)&Bs[(wc + t * 16 + cl) * 32 + gp * 8];
#pragma unroll
        for (int mt = 0; mt < 4; mt++)
#pragma unroll
            for (int nt = 0; nt < 2; nt++)
                acc[mt][nt] = mfma16(af[mt], bfr[nt], acc[mt][nt]);
    }
    int r0 = gp * 4;
#pragma unroll
    for (int mt = 0; mt < 4; mt++)
#pragma unroll
        for (int nt = 0; nt < 2; nt++)
#pragma unroll
            for (int r = 0; r < 4; r++) {
                int row = m0 + wr + mt * 16 + r0 + r;
                int col = n0 + wc + nt * 16 + cl;
                Cc[(size_t)row * N + col] = acc[mt][nt][r];
            }
}

// 6. norm_rope (0..2047) + V transpose (2048..2303) merged.
__global__ __launch_bounds__(256) void k_nrv(const float* __restrict__ qkv,
                                             const float* __restrict__ lnw,
                                             uint16_t* __restrict__ Qh,
                                             uint16_t* __restrict__ Kh,
                                             uint16_t* __restrict__ Vt) {
    __shared__ float tile[64][65];
    int blk = blockIdx.x, tid = threadIdx.x;
    if (blk >= 2048) {                 // V transpose, kv-swizzled
        int v = blk - 2048;
        int bh = v >> 4, kt = v & 15;
        int b = bh >> 3, h = bh & 7;
        int r = tid >> 2, cg = tid & 3;
        const float* srow = qkv + ((size_t)(b * 1024 + kt * 64 + r)) * 2048 + 1536 + h * 64 + cg * 16;
#pragma unroll
        for (int p = 0; p < 4; p++) {
            float4 vv = *(const float4*)(srow + p * 4);
            tile[r][cg * 16 + p * 4 + 0] = vv.x;
            tile[r][cg * 16 + p * 4 + 1] = vv.y;
            tile[r][cg * 16 + p * 4 + 2] = vv.z;
            tile[r][cg * 16 + p * 4 + 3] = vv.w;
        }
        __syncthreads();
        int d = tid >> 2, t4 = tid & 3;
        uint16_t* drow = Vt + ((size_t)(bh * 64 + d)) * 1024 + kt * 64;
#pragma unroll
        for (int g = 0; g < 4; g++) {
            uint16_t pk[4];
#pragma unroll
            for (int j = 0; j < 4; j++) pk[j] = f2bf(tile[t4 * 16 + g * 4 + j][d]);
            *(uint2*)&drow[g * 16 + t4 * 4] = *(const uint2*)pk;
        }
        return;
    }
    // RMSNorm + RoPE -> Q (e=0,1) and K (pre-scaled 1/8)
    int b = blk >> 10, i = blk & 1023;
    int lane = tid & 63, w = tid >> 6;
    float* red = &tile[0][0];
    const float* row = qkv + (size_t)blk * 2048;
    int c0 = tid * 2;
    int d0 = c0 & 63, head = c0 >> 6;
    int j0 = d0 & 31, j1 = (d0 + 1) & 31;
    const float LN1E4_64 = 0.14391156831212787f;   // ln(10000)/64
    float fi = (float)i;
    float ang0 = fi * __expf(-(float)(4 * j0 + 1) * LN1E4_64);
    float ang1 = fi * __expf(-(float)(4 * j1 + 1) * LN1E4_64);
    float c_0 = cosf(ang0), s_0 = sinf(ang0);
    float c_1 = cosf(ang1), s_1 = sinf(ang1);
    float g0 = lnw[c0], g1 = lnw[c0 + 1];
    for (int which = 0; which < 3; which++) {        // q(e=0), q(e=1), k
        int off = which * 512;
        float u0 = row[off + c0], u1 = row[off + c0 + 1];
        float ss = u0 * u0 + u1 * u1;
        for (int m = 1; m < 64; m <<= 1) ss += __shfl_xor(ss, m);
        __syncthreads();
        if (lane == 0) red[w] = ss;
        __syncthreads();
        float tot = red[0] + red[1] + red[2] + red[3];
        float rinv = rsqrtf(tot * (1.0f / 512.0f) + 1e-6f);
        float n0 = u0 * rinv * g0, n1 = u1 * rinv * g1;
        float r0 = n0 * c_0 - n1 * s_0;              // even dim
        float r1 = n1 * c_1 + n0 * s_1;              // odd dim (different angle!)
        if (which < 2) {
            uint32_t pk = (uint32_t)f2bf(r0) | ((uint32_t)f2bf(r1) << 16);
            uint16_t* dstp = Qh + ((size_t)((b * 2 + which) * 8 + head) * 1024 + i) * 64 + d0;
            *(uint32_t*)dstp = pk;
        } else {                                     // K: fold 1/sqrt(hs)
            uint32_t pk = (uint32_t)f2bf(r0 * 0.125f) | ((uint32_t)f2bf(r1 * 0.125f) << 16);
            uint16_t* dstp = Kh + ((size_t)(b * 8 + head) * 1024 + i) * 64 + d0;
            *(uint32_t*)dstp = pk;
        }
    }
}

// 7. causal flash attention, EXPERT-SHARED K/V + CROSS-TILE K-PREFETCH:
//    block=(qt desc, b*8+h); wave loads K/V once, computes both experts.
//    K of tile j+1 is loaded during compute of tile j (K is consumed at tile
//    start -> its L2 latency was the exposed stall; V already hides under QK).
//    8 waves = 2 q-groups x 4 KV-splits; fixed-shift softmax p=exp(s-8).
__global__ __launch_bounds__(512, 2) void k_attn(const uint16_t* __restrict__ Qh,
                                                 const uint16_t* __restrict__ Kh,
                                                 const uint16_t* __restrict__ Vt,
                                                 uint16_t* __restrict__ ybf) {
    __shared__ float cb[2][3][2][64][17];   // [e][ws-1][wq][lane][o16+ls]
    int blk = blockIdx.x;
    int qt = 31 - (blk >> 4);          // big q-tiles first
    int inst = blk & 15;               // b*8+h
    int h = inst & 7, b = inst >> 3;
    int tid = threadIdx.x, lane = tid & 63, w = tid >> 6;
    int wq = w & 1, ws = w >> 1;       // q-group (2), kv-split (4)
    int qw = qt * 32 + wq * 16;
    const uint16_t* Kb = Kh + (size_t)inst * 1024 * 64;
    const uint16_t* Vb = Vt + (size_t)inst * 64 * 1024;
    int cl = lane & 15, gp = lane >> 4;
    const uint16_t* Qb0 = Qh + ((size_t)((b * 2 + 0) * 8 + h) * 1024 + qw) * 64;
    const uint16_t* Qb1 = Qh + ((size_t)((b * 2 + 1) * 8 + h) * 1024 + qw) * 64;
    bf16x8 qf00 = *(const bf16x8*)&Qb0[cl * 64 + gp * 8];
    bf16x8 qf01 = *(const bf16x8*)&Qb0[cl * 64 + 32 + gp * 8];
    bf16x8 qf10 = *(const bf16x8*)&Qb1[cl * 64 + gp * 8];
    bf16x8 qf11 = *(const bf16x8*)&Qb1[cl * 64 + 32 + gp * 8];
    f32x4 o0[4], o1[4];
#pragma unroll
    for (int dt = 0; dt < 4; dt++)
#pragma unroll
        for (int r = 0; r < 4; r++) { o0[dt][r] = 0.f; o1[dt][r] = 0.f; }
    float ls0 = 0.f, ls1 = 0.f;
    int qa = qw + cl;
    const float L2E = 1.44269504f;     // log2(e)
    const float SH  = -11.5415603f;    // -8*log2(e)

    int jt = ws * 64;
    bf16x8 nk[8];                      // next-tile K (prefetched)
    if (jt <= qw) {
#pragma unroll
        for (int t = 0; t < 4; t++) {
            const uint16_t* kr = &Kb[(size_t)(jt + t * 16 + cl) * 64 + gp * 8];
            nk[t * 2]     = *(const bf16x8*)kr;
            nk[t * 2 + 1] = *(const bf16x8*)(kr + 32);
        }
    }
    for (; jt <= qw; jt += 256) {
        // current K = prefetched; issue V(cur) then K(next) before compute
        bf16x8 ck[8];
#pragma unroll
        for (int i = 0; i < 8; i++) ck[i] = nk[i];
        s16x8 vv0[4], vv1[4];
#pragma unroll
        for (int dt = 0; dt < 4; dt++) {
            const uint16_t* vrow = &Vb[(size_t)(dt * 16 + cl) * 1024 + jt + gp * 16];
            vv0[dt] = *(const s16x8*)vrow;
            vv1[dt] = *(const s16x8*)(vrow + 8);
        }
        int jn = jt + 256;
        if (jn <= qw) {
#pragma unroll
            for (int t = 0; t < 4; t++) {
                const uint16_t* kr = &Kb[(size_t)(jn + t * 16 + cl) * 64 + gp * 8];
                nk[t * 2]     = *(const bf16x8*)kr;
                nk[t * 2 + 1] = *(const bf16x8*)(kr + 32);
            }
        }
        bool bnd = (jt + 63 > qw);
#pragma unroll
        for (int e = 0; e < 2; e++) {
            bf16x8 qa0 = e ? qf10 : qf00;
            bf16x8 qa1 = e ? qf11 : qf01;
            f32x4 sv[4];
#pragma unroll
            for (int t = 0; t < 4; t++)
#pragma unroll
                for (int r = 0; r < 4; r++) sv[t][r] = 0.f;
            sv[0] = mfma16(ck[0], qa0, sv[0]); sv[0] = mfma16(ck[1], qa1, sv[0]);
            sv[1] = mfma16(ck[2], qa0, sv[1]); sv[1] = mfma16(ck[3], qa1, sv[1]);
            sv[2] = mfma16(ck[4], qa0, sv[2]); sv[2] = mfma16(ck[5], qa1, sv[2]);
            sv[3] = mfma16(ck[6], qa0, sv[3]); sv[3] = mfma16(ck[7], qa1, sv[3]);
            float lsl = 0.f;
            s16x4 pb[4];
#pragma unroll
            for (int t = 0; t < 4; t++) {
                union { s16x4 s4; __bf16 bf[4]; } pu;
#pragma unroll
                for (int r = 0; r < 4; r++) {
                    float p = exp2f(fmaf(sv[t][r], L2E, SH));   // exp(s-8)
                    if (bnd) {
                        int kv = jt + t * 16 + gp * 4 + r;
                        p = (kv <= qa) ? p : 0.f;
                    }
                    lsl += p;
                    pu.bf[r] = (__bf16)p;
                }
                pb[t] = pu.s4;
            }
            if (e == 0) ls0 += lsl; else ls1 += lsl;
#pragma unroll
            for (int dt = 0; dt < 4; dt++) {
                s16x4 a0 = __builtin_shufflevector(vv0[dt], vv0[dt], 0, 1, 2, 3);
                s16x4 a1 = __builtin_shufflevector(vv0[dt], vv0[dt], 4, 5, 6, 7);
                s16x4 a2 = __builtin_shufflevector(vv1[dt], vv1[dt], 0, 1, 2, 3);
                s16x4 a3 = __builtin_shufflevector(vv1[dt], vv1[dt], 4, 5, 6, 7);
                f32x4 oo = e ? o1[dt] : o0[dt];
                oo = mfma_k16(a0, pb[0], oo);
                oo = mfma_k16(a1, pb[1], oo);
                oo = mfma_k16(a2, pb[2], oo);
                oo = mfma_k16(a3, pb[3], oo);
                if (e == 0) o0[dt] = oo; else o1[dt] = oo;
            }
        }
    }
    ls0 += __shfl_xor(ls0, 16); ls0 += __shfl_xor(ls0, 32);
    ls1 += __shfl_xor(ls1, 16); ls1 += __shfl_xor(ls1, 32);
    if (ws != 0) {
#pragma unroll
        for (int dt = 0; dt < 4; dt++)
#pragma unroll
            for (int r = 0; r < 4; r++) {
                cb[0][ws - 1][wq][lane][dt * 4 + r] = o0[dt][r];
                cb[1][ws - 1][wq][lane][dt * 4 + r] = o1[dt][r];
            }
        cb[0][ws - 1][wq][lane][16] = ls0;
        cb[1][ws - 1][wq][lane][16] = ls1;
    }
    __syncthreads();
    if (ws == 0) {
#pragma unroll
        for (int e = 0; e < 2; e++) {
            float lse = e ? ls1 : ls0;
            float lst = lse + cb[e][0][wq][lane][16] + cb[e][1][wq][lane][16]
                            + cb[e][2][wq][lane][16];
            float inv = 1.f / lst;
            uint16_t* yb = ybf + ((size_t)((b * 2 + e) * 1024 + qw)) * 512 + h * 64;
#pragma unroll
            for (int dt = 0; dt < 4; dt++) {
                uint16_t pk[4];
#pragma unroll
                for (int r = 0; r < 4; r++) {
                    float base = e ? o1[dt][r] : o0[dt][r];
                    float v = base + cb[e][0][wq][lane][dt * 4 + r]
                                   + cb[e][1][wq][lane][dt * 4 + r]
                                   + cb[e][2][wq][lane][dt * 4 + r];
                    pk[r] = f2bf(v * inv);
                }
                *(uint2*)&yb[(size_t)cl * 512 + dt * 16 + gp * 4] = *(const uint2*)pk;
            }
        }
    }
}

// 8. fused proj-GEMM + gated combine (direct store) + BCE loss (pid==32 row).
__global__ __launch_bounds__(256) void k_projc(const uint16_t* __restrict__ ybf,
                                               const uint16_t* __restrict__ Wprojt,
                                               const int* __restrict__ idx,
                                               const float* __restrict__ wsel,
                                               const float* __restrict__ gate,
                                               const float* __restrict__ x,
                                               const float* __restrict__ pl,
                                               const int* __restrict__ mask,
                                               float* __restrict__ out) {
    __shared__ uint16_t As0[64 * 40], As1[64 * 40], Bs[64 * 40];
    int pid = blockIdx.x;              // 0..32
    int tid = threadIdx.x;
    if (pid == 32) {                   // BCE loss (one block; only y==0 works)
        if (blockIdx.y != 0) return;
        __shared__ float red[4];
        int lane = tid & 63, wl = tid >> 6;
        float s = 0.f;
#pragma unroll
        for (int j = 0; j < 16; j++) {
            int i = tid * 16 + j;
            float p = pl[i];
            float tgt = (float)mask[i];
            s += fmaxf(p, 0.f) - p * tgt + log1pf(__expf(-fabsf(p)));
        }
        for (int mm = 1; mm < 64; mm <<= 1) s += __shfl_xor(s, mm);
        if (lane == 0) red[wl] = s;
        __syncthreads();
        if (tid == 0)
            out[2097152] = (red[0] + red[1] + red[2] + red[3]) * (1.0f / 4096.0f);
        return;
    }
    int b = pid >> 4, pos0 = (pid & 15) * 64;
    int n0 = blockIdx.y * 64;
    int lane = tid & 63, w = tid >> 6;
    int cl = lane & 15, gp = lane >> 4;
    f32x4 acc0[4], acc1[4];
#pragma unroll
    for (int nt = 0; nt < 4; nt++)
#pragma unroll
        for (int r = 0; r < 4; r++) { acc0[nt][r] = 0.f; acc1[nt][r] = 0.f; }
    int arow = tid >> 2, akg = tid & 3;
    const bf16x8* A8 = (const bf16x8*)ybf;
    const bf16x8* B8 = (const bf16x8*)Wprojt;
    size_t rowe0 = (size_t)(b * 2) * 1024 + pos0 + arow;
    for (int ks = 0; ks < 512; ks += 32) {
        __syncthreads();
        int kc = (ks >> 3) + akg;
        bf16x8 va0 = A8[rowe0 * 64 + kc];
        bf16x8 va1 = A8[(rowe0 + 1024) * 64 + kc];
        bf16x8 vb  = B8[(size_t)(n0 + arow) * 64 + kc];
        *(bf16x8*)&As0[arow * 40 + akg * 8] = va0;
        *(bf16x8*)&As1[arow * 40 + akg * 8] = va1;
        *(bf16x8*)&Bs[arow * 40 + akg * 8]  = vb;
        __syncthreads();
        bf16x8 a0 = *(const bf16x8*)&As0[(w * 16 + cl) * 40 + gp * 8];
        bf16x8 a1 = *(const bf16x8*)&As1[(w * 16 + cl) * 40 + gp * 8];
#pragma unroll
        for (int nt = 0; nt < 4; nt++) {
            bf16x8 bfr = *(const bf16x8*)&Bs[(nt * 16 + cl) * 40 + gp * 8];
            acc0[nt] = mfma16(a0, bfr, acc0[nt]);
            acc1[nt] = mfma16(a1, bfr, acc1[nt]);
        }
    }
#pragma unroll
    for (int r = 0; r < 4; r++) {
        int pos = pos0 + w * 16 + gp * 4 + r;
        int bk = b * 1024 + pos;
        int t = idx[bk];
        float wv = wsel[bk], g0 = gate[bk * 2], g1 = gate[bk * 2 + 1];
        const float* xrow = x + ((size_t)(b * 2048 + t)) * 512;
        float* orow = out + ((size_t)(b * 2048 + t)) * 512;
#pragma unroll
        for (int nt = 0; nt < 4; nt++) {
            int col = n0 + nt * 16 + cl;
            orow[col] = xrow[col] + wv * (g0 * acc0[nt][r] + g1 * acc1[nt][r]);
        }
    }
}

// ---------------------------------------------------------------------------
extern "C" void kernel_launch(void* const* d_in, const int* in_sizes, int n_in,
                              void* d_out, int out_size, void* d_ws, size_t ws_size,
                              hipStream_t stream) {
    const float* x        = (const float*)d_in[0];
    const float* W_router = (const float*)d_in[1];
    const float* W_q      = (const float*)d_in[2];
    const float* W_kv     = (const float*)d_in[3];
    const float* W_proj   = (const float*)d_in[4];
    const float* ln_w     = (const float*)d_in[5];
    const float* W_gate   = (const float*)d_in[6];
    const float* W_pred   = (const float*)d_in[7];

    char* ws = (char*)d_ws;
    float*    logits = (float*)   (ws + OFF_LOGITS);
    float*    pl     = (float*)   (ws + OFF_PL);
    int*      mask   = (int*)     (ws + OFF_MASK);
    int*      posmap = (int*)     (ws + OFF_POSMAP);
    int*      idx    = (int*)     (ws + OFF_IDX);
    float*    wsel   = (float*)   (ws + OFF_WSEL);
    float*    gate   = (float*)   (ws + OFF_GATE);
    uint16_t* selbf  = (uint16_t*)(ws + OFF_SELBF);
    uint16_t* Wqkvt  = (uint16_t*)(ws + OFF_WQKVT);
    uint16_t* Wprojt = (uint16_t*)(ws + OFF_WPROJT);
    float*    qkvraw = (float*)   (ws + OFF_QKVRAW);
    uint16_t* Qh     = (uint16_t*)(ws + OFF_QH);
    uint16_t* Kh     = (uint16_t*)(ws + OFF_KH);
    uint16_t* Vt     = (uint16_t*)(ws + OFF_VT);
    uint16_t* ybf    = (uint16_t*)(ws + OFF_YBF);
    float*    out    = (float*)d_out;

    k_prep       <<<1344, 256, 0, stream>>>(W_q, W_kv, W_proj, Wqkvt, Wprojt,
                                            x, W_router, W_pred, logits, pl);
    k_rank       <<<1024, 256, 0, stream>>>(logits, mask);
    k_select     <<<2, 1024, 0, stream>>>(logits, mask, idx, wsel, posmap);
    k_gather_gate<<<4096, 256, 0, stream>>>(x, idx, W_gate, posmap, selbf, gate, out);
    k_gemm       <<<dim3(16, 32), 256, 0, stream>>>(selbf, Wqkvt, qkvraw, 2048, 2048, 512);
    k_nrv        <<<2304, 256, 0, stream>>>(qkvraw, ln_w, Qh, Kh, Vt);
    k_attn       <<<512, 512, 0, stream>>>(Qh, Kh, Vt, ybf);
    k_projc      <<<dim3(33, 8), 256, 0, stream>>>(ybf, Wprojt, idx, wsel, gate, x,
                                                   pl, mask, out);
}

// Round 17
// 82.162 us; speedup vs baseline: 1.0019x; 1.0019x over previous
//
#include <hip/hip_runtime.h>
#include <cstdint>

// ---------------------------------------------------------------------------
// MoDBlock: B=2, T=2048, C=512, E=2, NH=8, hs=64, k=1024 (hardcoded).
// Output: out [B,T,C] f32 (2097152) + loss (1).
// R13 structure + V-path fused into GEMM epilogue (direct swizzled Vt write).
// ---------------------------------------------------------------------------

#define DI __device__ __forceinline__

typedef __bf16 bf16x8 __attribute__((ext_vector_type(8)));
typedef float  f32x4  __attribute__((ext_vector_type(4)));
typedef short  s16x4  __attribute__((ext_vector_type(4)));
typedef short  s16x8  __attribute__((ext_vector_type(8)));

DI uint16_t f2bf(float f) {
    union { float f; uint32_t u; } v; v.f = f;
    uint32_t u = v.u;
    uint32_t r = (u + 0x7FFFu + ((u >> 16) & 1u)) >> 16;   // RNE; finite inputs only
    return (uint16_t)r;
}

DI f32x4 mfma16(bf16x8 a, bf16x8 b, f32x4 c) {
    return __builtin_amdgcn_mfma_f32_16x16x32_bf16(a, b, c, 0, 0, 0);
}
DI f32x4 mfma_k16(s16x4 a, s16x4 b, f32x4 c) {
    return __builtin_amdgcn_mfma_f32_16x16x16bf16_1k(a, b, c, 0, 0, 0);
}
DI void gload16(const void* g, void* l) {       // async 16B/lane global->LDS
    __builtin_amdgcn_global_load_lds(
        (const __attribute__((address_space(1))) uint32_t*)g,
        (__attribute__((address_space(3))) uint32_t*)l, 16, 0, 0);
}

// ---- workspace layout (bytes) ----
constexpr size_t OFF_LOGITS = 0;                                // 4096 f32
constexpr size_t OFF_PL     = OFF_LOGITS + 4096 * 4;            // 4096 f32
constexpr size_t OFF_MASK   = OFF_PL     + 4096 * 4;            // 4096 int
constexpr size_t OFF_POSMAP = OFF_MASK   + 4096 * 4;            // 4096 int
constexpr size_t OFF_IDX    = OFF_POSMAP + 4096 * 4;            // 2048 int
constexpr size_t OFF_WSEL   = OFF_IDX    + 2048 * 4;            // 2048 f32
constexpr size_t OFF_GATE   = OFF_WSEL   + 2048 * 4;            // 2048*2 f32
constexpr size_t OFF_SELBF  = OFF_GATE   + 4096 * 4;            // 2048*512 bf16
constexpr size_t OFF_WQKVT  = OFF_SELBF  + 2048 * 512 * 2;      // [2048][512] bf16
constexpr size_t OFF_WPROJT = OFF_WQKVT  + 2048 * 512 * 2;      // [512][512] bf16
constexpr size_t OFF_QKVRAW = OFF_WPROJT + 512 * 512 * 2;       // 2048*2048 f32
constexpr size_t OFF_QH     = OFF_QKVRAW + (size_t)2048 * 2048 * 4; // [B,E,NH,k,64] bf16
constexpr size_t OFF_KH     = OFF_QH     + (size_t)2097152 * 2;     // [B,NH,k,64] bf16 (pre-scaled 1/8)
constexpr size_t OFF_VT     = OFF_KH     + (size_t)1048576 * 2;     // [B,NH,64,k] bf16 (kv-swizzled)
constexpr size_t OFF_YBF    = OFF_VT     + (size_t)1048576 * 2;     // [B,E,k,512] bf16

// ---------------------------------------------------------------------------
// 1. prep: weight transpose+cast (0..319) + router/predictor logits (320..1343).
__global__ __launch_bounds__(256) void k_prep(const float* __restrict__ Wq,
                                              const float* __restrict__ Wkv,
                                              const float* __restrict__ Wp,
                                              uint16_t* __restrict__ Wqkvt,
                                              uint16_t* __restrict__ Wprojt,
                                              const float* __restrict__ x,
                                              const float* __restrict__ wr,
                                              const float* __restrict__ wp,
                                              float* __restrict__ logits,
                                              float* __restrict__ pl) {
    __shared__ float tile[64][65];
    int blk = blockIdx.x, tid = threadIdx.x;
    if (blk >= 320) {                  // router + predictor logits
        int rblk = blk - 320;
        int wid  = rblk * 4 + (tid >> 6);
        int lane = tid & 63;
        const float* xr = x + (size_t)wid * 512;
        double s = 0.0; float sp = 0.f;
#pragma unroll
        for (int j = 0; j < 8; j++) {
            int c = lane + 64 * j;
            float xv = xr[c];
            s  += (double)xv * (double)wr[c];
            sp += xv * wp[c];
        }
        for (int m = 1; m < 64; m <<= 1) { s += __shfl_xor(s, m); sp += __shfl_xor(sp, m); }
        if (lane == 0) { logits[wid] = (float)s; pl[wid] = sp; }
        return;
    }
    const float* src; uint16_t* dst; int n0, c0, ldn;
    if (blk < 256) {                   // qkv: dest [2048][512]
        int tn = blk & 31, tc = blk >> 5;
        n0 = tn * 64; c0 = tc * 64; ldn = 1024;
        if (n0 < 1024) { src = Wq; } else { src = Wkv; n0 -= 1024; }
        dst = Wqkvt + (size_t)(tn * 64) * 512 + c0;
    } else {                           // proj: dest [512][512]
        int j = blk - 256; int tn = j & 7, tc = j >> 3;
        n0 = tn * 64; c0 = tc * 64; ldn = 512;
        src = Wp; dst = Wprojt + (size_t)n0 * 512 + c0;
    }
    int nl = tid & 63, cb = tid >> 6;
#pragma unroll
    for (int p = 0; p < 16; p++) {
        int cl_ = p * 4 + cb;
        tile[cl_][nl] = src[(size_t)(c0 + cl_) * ldn + n0 + nl];
    }
    __syncthreads();
    int cp = tid & 31, nb = tid >> 5;
#pragma unroll
    for (int p = 0; p < 8; p++) {
        int nl2 = p * 8 + nb;
        uint32_t pk = (uint32_t)f2bf(tile[cp * 2][nl2]) |
                      ((uint32_t)f2bf(tile[cp * 2 + 1][nl2]) << 16);
        *(uint32_t*)&dst[(size_t)nl2 * 512 + cp * 2] = pk;
    }
}

// 2. rank: count of strictly-greater (or equal with smaller index) -> mask
__global__ void k_rank(const float* __restrict__ logits, int* __restrict__ mask) {
    int wid  = (blockIdx.x * blockDim.x + threadIdx.x) >> 6;
    int lane = threadIdx.x & 63;
    if (wid >= 4096) return;
    int b = wid >> 11, t = wid & 2047;
    const float* lb = logits + b * 2048;
    float v = lb[t];
    int cnt = 0;
    for (int j = 0; j < 32; j++) {
        int tp = lane + 64 * j;
        float lv = lb[tp];
        bool pred = (lv > v) || (lv == v && tp < t);
        cnt += __popcll(__ballot(pred));
    }
    if (lane == 0) mask[wid] = (cnt < 1024) ? 1 : 0;
}

// 3. wave-scan selection: idx (temporal order), wsel, posmap. 1 block/batch.
__global__ void k_select(const float* __restrict__ logits, const int* __restrict__ mask,
                         int* __restrict__ idx, float* __restrict__ wsel,
                         int* __restrict__ posmap) {
    __shared__ int wsum[16], woff[16];
    int b = blockIdx.x, tid = threadIdx.x, lane = tid & 63, w = tid >> 6;
    int t0 = tid * 2, t1 = tid * 2 + 1;
    int m0 = mask[b * 2048 + t0], m1 = mask[b * 2048 + t1];
    int s = m0 + m1;
    int sc = s;
    for (int off = 1; off < 64; off <<= 1) {
        int v = __shfl_up(sc, off);
        if (lane >= off) sc += v;
    }
    if (lane == 63) wsum[w] = sc;
    __syncthreads();
    if (tid < 16) {
        int acc = 0;
        for (int j = 0; j < tid; j++) acc += wsum[j];
        woff[tid] = acc;
    }
    __syncthreads();
    int excl = woff[w] + sc - s;
    int p0 = excl, p1 = excl + m0;
    if (m0) {
        idx[b * 1024 + p0] = t0;
        float v = logits[b * 2048 + t0];
        wsel[b * 1024 + p0] = 1.f / (1.f + __expf(-v));
    }
    posmap[b * 2048 + t0] = m0 ? p0 : -1;
    if (m1) {
        idx[b * 1024 + p1] = t1;
        float v = logits[b * 2048 + t1];
        wsel[b * 1024 + p1] = 1.f / (1.f + __expf(-v));
    }
    posmap[b * 2048 + t1] = m1 ? p1 : -1;
}

// 4. gather selected rows -> bf16 + gate (blk<2048); copy UNSELECTED rows x->out
//    (blk in [2048,4096): 2 rows/block over ALL 4096 rows, posmap<0 only).
__global__ void k_gather_gate(const float* __restrict__ x, const int* __restrict__ idx,
                              const float* __restrict__ Wg, const int* __restrict__ posmap,
                              uint16_t* __restrict__ selbf, float* __restrict__ gate,
                              float* __restrict__ out) {
    __shared__ float red0[4], red1[4];
    int blk = blockIdx.x;
    int tid = threadIdx.x, lane = tid & 63, w = tid >> 6;
    if (blk >= 2048) {                 // copy phase: rows 0..4095
        int row = (blk - 2048) * 2 + (tid >> 7);   // 2 rows/block, 2048 blocks
        int ci = tid & 127;
        if (posmap[row] < 0) {
            const float4* xr = (const float4*)(x + (size_t)row * 512);
            float4* orow = (float4*)(out + (size_t)row * 512);
            orow[ci] = xr[ci];
        }
        return;
    }
    int b = blk >> 10;
    int t = idx[blk];
    const float* xr = x + ((size_t)b * 2048 + t) * 512;
    int c = tid * 2;
    float v0 = xr[c], v1 = xr[c + 1];
    uint32_t pk = (uint32_t)f2bf(v0) | ((uint32_t)f2bf(v1) << 16);
    ((uint32_t*)(selbf + (size_t)blk * 512))[tid] = pk;
    float g0 = v0 * Wg[c * 2]     + v1 * Wg[(c + 1) * 2];
    float g1 = v0 * Wg[c * 2 + 1] + v1 * Wg[(c + 1) * 2 + 1];
    for (int m = 1; m < 64; m <<= 1) { g0 += __shfl_xor(g0, m); g1 += __shfl_xor(g1, m); }
    if (lane == 0) { red0[w] = g0; red1[w] = g1; }
    __syncthreads();
    if (tid == 0) {
        float a = red0[0] + red0[1] + red0[2] + red0[3];
        float bq = red1[0] + red1[1] + red1[2] + red1[3];
        float mx = fmaxf(a, bq);
        float ea = __expf(a - mx), eb = __expf(bq - mx), s = ea + eb;
        gate[blk * 2] = ea / s; gate[blk * 2 + 1] = eb / s;
    }
}

// 5. bf16 MFMA GEMM (QKV): C[M,2048] f32 = A[M,512] @ Bt^T, with V-region
//    (cols 1536..2047) written DIRECTLY to Vt bf16 in the kv-swizzled
//    transposed layout (t=mt, g=gp, j=r decomposition; wave-uniform branch).
__global__ __launch_bounds__(256) void k_gemm(const uint16_t* __restrict__ A,
                                              const uint16_t* __restrict__ Bt,
                                              float* __restrict__ Cc,
                                              uint16_t* __restrict__ Vt,
                                              int M, int N, int Kd) {
    __shared__ uint16_t As[128 * 32];   // 8 KB
    __shared__ uint16_t Bs[64 * 32];    // 4 KB
    int tid = threadIdx.x, lane = tid & 63, w = tid >> 6;
    int m0 = blockIdx.x * 128, n0 = blockIdx.y * 64;
    int wr = (w >> 1) * 64, wc = (w & 1) * 32;
    int cl = lane & 15, gp = lane >> 4;
    f32x4 acc[4][2];
#pragma unroll
    for (int mt = 0; mt < 4; mt++)
#pragma unroll
        for (int nt = 0; nt < 2; nt++)
#pragma unroll
            for (int r = 0; r < 4; r++) acc[mt][nt][r] = 0.f;
    int srow = lane >> 2, skc = (lane & 3) * 8;
    for (int ks = 0; ks < Kd; ks += 32) {
        __syncthreads();
        const uint16_t* ga0 = A + (size_t)(m0 + w * 32 + srow) * Kd + ks + skc;
        gload16(ga0, &As[(w * 32) * 32]);
        gload16(ga0 + (size_t)16 * Kd, &As[(w * 32 + 16) * 32]);
        const uint16_t* gb = Bt + (size_t)(n0 + w * 16 + srow) * Kd + ks + skc;
        gload16(gb, &Bs[(w * 16) * 32]);
        __syncthreads();
        bf16x8 af[4], bfr[2];
#pragma unroll
        for (int t = 0; t < 4; t++)
            af[t] = *(const bf16x8*)&As[(wr + t * 16 + cl) * 32 + gp * 8];
#pragma unroll
        for (int t = 0; t < 2; t++)
            bfr[t] = *(const bf16x8*)&Bs[(wc + t * 16 + cl) * 32 + gp * 8];
#pragma unroll
        for (int mt = 0; mt < 4; mt++)
#pragma unroll
            for (int nt = 0; nt < 2; nt++)
                acc[mt][nt] = mfma16(af[mt], bfr[nt], acc[mt][nt]);
    }
    int r0 = gp * 4;
#pragma unroll
    for (int mt = 0; mt < 4; mt++)
#pragma unroll
        for (int nt = 0; nt < 2; nt++) {
            int colb = n0 + wc + nt * 16;          // 16-col group base (uniform)
            if (colb >= 1536) {                    // V region -> direct Vt write
                int row0 = m0 + wr + mt * 16 + r0; // r=0 row; 4 rows same 64-chunk
                int bq = row0 >> 10, i0 = row0 & 1023;
                int cc2 = colb + cl - 1536, hh = cc2 >> 6, dd = cc2 & 63;
                uint16_t pk[4];
#pragma unroll
                for (int r = 0; r < 4; r++) pk[r] = f2bf(acc[mt][nt][r]);
                size_t vidx = ((size_t)((bq * 8 + hh) * 64 + dd)) * 1024
                              + (i0 & ~63) + gp * 16 + mt * 4;
                *(uint2*)&Vt[vidx] = *(const uint2*)pk;
            } else {
#pragma unroll
                for (int r = 0; r < 4; r++) {
                    int row = m0 + wr + mt * 16 + r0 + r;
                    int col = colb + cl;
                    Cc[(size_t)row * N + col] = acc[mt][nt][r];
                }
            }
        }
}

// 6. RMSNorm + RoPE -> head-layout bf16 Q and K (K pre-scaled by 1/8).
//    (V handled by k_gemm epilogue now.)
__global__ __launch_bounds__(256) void k_nrv(const float* __restrict__ qkv,
                                             const float* __restrict__ lnw,
                                             uint16_t* __restrict__ Qh,
                                             uint16_t* __restrict__ Kh) {
    __shared__ float red[4];
    int blk = blockIdx.x, tid = threadIdx.x;
    int b = blk >> 10, i = blk & 1023;
    int lane = tid & 63, w = tid >> 6;
    const float* row = qkv + (size_t)blk * 2048;
    int c0 = tid * 2;
    int d0 = c0 & 63, head = c0 >> 6;
    int j0 = d0 & 31, j1 = (d0 + 1) & 31;
    const float LN1E4_64 = 0.14391156831212787f;   // ln(10000)/64
    float fi = (float)i;
    float ang0 = fi * __expf(-(float)(4 * j0 + 1) * LN1E4_64);
    float ang1 = fi * __expf(-(float)(4 * j1 + 1) * LN1E4_64);
    float c_0 = cosf(ang0), s_0 = sinf(ang0);
    float c_1 = cosf(ang1), s_1 = sinf(ang1);
    float g0 = lnw[c0], g1 = lnw[c0 + 1];
    for (int which = 0; which < 3; which++) {        // q(e=0), q(e=1), k
        int off = which * 512;
        float u0 = row[off + c0], u1 = row[off + c0 + 1];
        float ss = u0 * u0 + u1 * u1;
        for (int m = 1; m < 64; m <<= 1) ss += __shfl_xor(ss, m);
        __syncthreads();
        if (lane == 0) red[w] = ss;
        __syncthreads();
        float tot = red[0] + red[1] + red[2] + red[3];
        float rinv = rsqrtf(tot * (1.0f / 512.0f) + 1e-6f);
        float n0 = u0 * rinv * g0, n1 = u1 * rinv * g1;
        float r0 = n0 * c_0 - n1 * s_0;              // even dim
        float r1 = n1 * c_1 + n0 * s_1;              // odd dim (different angle!)
        if (which < 2) {
            uint32_t pk = (uint32_t)f2bf(r0) | ((uint32_t)f2bf(r1) << 16);
            uint16_t* dstp = Qh + ((size_t)((b * 2 + which) * 8 + head) * 1024 + i) * 64 + d0;
            *(uint32_t*)dstp = pk;
        } else {                                     // K: fold 1/sqrt(hs)
            uint32_t pk = (uint32_t)f2bf(r0 * 0.125f) | ((uint32_t)f2bf(r1 * 0.125f) << 16);
            uint16_t* dstp = Kh + ((size_t)(b * 8 + head) * 1024 + i) * 64 + d0;
            *(uint32_t*)dstp = pk;
        }
    }
}

// 7. causal flash attention, EXPERT-SHARED K/V (R13-proven): block=(qt desc,
//    b*8+h); wave loads K/V once, computes both experts. 8 waves = 2 q-groups
//    x 4 KV-splits; fixed-shift softmax p=exp(s-8); LDS split-combine.
__global__ __launch_bounds__(512, 2) void k_attn(const uint16_t* __restrict__ Qh,
                                                 const uint16_t* __restrict__ Kh,
                                                 const uint16_t* __restrict__ Vt,
                                                 uint16_t* __restrict__ ybf) {
    __shared__ float cb[2][3][2][64][17];   // [e][ws-1][wq][lane][o16+ls]
    int blk = blockIdx.x;
    int qt = 31 - (blk >> 4);          // big q-tiles first
    int inst = blk & 15;               // b*8+h
    int h = inst & 7, b = inst >> 3;
    int tid = threadIdx.x, lane = tid & 63, w = tid >> 6;
    int wq = w & 1, ws = w >> 1;       // q-group (2), kv-split (4)
    int qw = qt * 32 + wq * 16;
    const uint16_t* Kb = Kh + (size_t)inst * 1024 * 64;
    const uint16_t* Vb = Vt + (size_t)inst * 64 * 1024;
    int cl = lane & 15, gp = lane >> 4;
    const uint16_t* Qb0 = Qh + ((size_t)((b * 2 + 0) * 8 + h) * 1024 + qw) * 64;
    const uint16_t* Qb1 = Qh + ((size_t)((b * 2 + 1) * 8 + h) * 1024 + qw) * 64;
    bf16x8 qf00 = *(const bf16x8*)&Qb0[cl * 64 + gp * 8];
    bf16x8 qf01 = *(const bf16x8*)&Qb0[cl * 64 + 32 + gp * 8];
    bf16x8 qf10 = *(const bf16x8*)&Qb1[cl * 64 + gp * 8];
    bf16x8 qf11 = *(const bf16x8*)&Qb1[cl * 64 + 32 + gp * 8];
    f32x4 o0[4], o1[4];
#pragma unroll
    for (int dt = 0; dt < 4; dt++)
#pragma unroll
        for (int r = 0; r < 4; r++) { o0[dt][r] = 0.f; o1[dt][r] = 0.f; }
    float ls0 = 0.f, ls1 = 0.f;
    int qa = qw + cl;
    const float L2E = 1.44269504f;     // log2(e)
    const float SH  = -11.5415603f;    // -8*log2(e)

    for (int jt = ws * 64; jt <= qw; jt += 256) {
        // K/V tile loaded ONCE, consumed by both experts
        s16x8 vv0[4], vv1[4];
        const uint16_t* kr0 = &Kb[(size_t)(jt + cl) * 64 + gp * 8];
        const uint16_t* kr1 = &Kb[(size_t)(jt + 16 + cl) * 64 + gp * 8];
        const uint16_t* kr2 = &Kb[(size_t)(jt + 32 + cl) * 64 + gp * 8];
        const uint16_t* kr3 = &Kb[(size_t)(jt + 48 + cl) * 64 + gp * 8];
        bf16x8 k00 = *(const bf16x8*)kr0, k01 = *(const bf16x8*)(kr0 + 32);
        bf16x8 k10 = *(const bf16x8*)kr1, k11 = *(const bf16x8*)(kr1 + 32);
        bf16x8 k20 = *(const bf16x8*)kr2, k21 = *(const bf16x8*)(kr2 + 32);
        bf16x8 k30 = *(const bf16x8*)kr3, k31 = *(const bf16x8*)(kr3 + 32);
#pragma unroll
        for (int dt = 0; dt < 4; dt++) {
            const uint16_t* vrow = &Vb[(size_t)(dt * 16 + cl) * 1024 + jt + gp * 16];
            vv0[dt] = *(const s16x8*)vrow;
            vv1[dt] = *(const s16x8*)(vrow + 8);
        }
        bool bnd = (jt + 63 > qw);
#pragma unroll
        for (int e = 0; e < 2; e++) {
            bf16x8 qa0 = e ? qf10 : qf00;
            bf16x8 qa1 = e ? qf11 : qf01;
            f32x4 sv[4];
#pragma unroll
            for (int t = 0; t < 4; t++)
#pragma unroll
                for (int r = 0; r < 4; r++) sv[t][r] = 0.f;
            sv[0] = mfma16(k00, qa0, sv[0]); sv[0] = mfma16(k01, qa1, sv[0]);
            sv[1] = mfma16(k10, qa0, sv[1]); sv[1] = mfma16(k11, qa1, sv[1]);
            sv[2] = mfma16(k20, qa0, sv[2]); sv[2] = mfma16(k21, qa1, sv[2]);
            sv[3] = mfma16(k30, qa0, sv[3]); sv[3] = mfma16(k31, qa1, sv[3]);
            float lsl = 0.f;
            s16x4 pb[4];
#pragma unroll
            for (int t = 0; t < 4; t++) {
                union { s16x4 s4; __bf16 bf[4]; } pu;
#pragma unroll
                for (int r = 0; r < 4; r++) {
                    float p = exp2f(fmaf(sv[t][r], L2E, SH));   // exp(s-8)
                    if (bnd) {
                        int kv = jt + t * 16 + gp * 4 + r;
                        p = (kv <= qa) ? p : 0.f;
                    }
                    lsl += p;
                    pu.bf[r] = (__bf16)p;
                }
                pb[t] = pu.s4;
            }
            if (e == 0) ls0 += lsl; else ls1 += lsl;
#pragma unroll
            for (int dt = 0; dt < 4; dt++) {
                s16x4 a0 = __builtin_shufflevector(vv0[dt], vv0[dt], 0, 1, 2, 3);
                s16x4 a1 = __builtin_shufflevector(vv0[dt], vv0[dt], 4, 5, 6, 7);
                s16x4 a2 = __builtin_shufflevector(vv1[dt], vv1[dt], 0, 1, 2, 3);
                s16x4 a3 = __builtin_shufflevector(vv1[dt], vv1[dt], 4, 5, 6, 7);
                f32x4 oo = e ? o1[dt] : o0[dt];
                oo = mfma_k16(a0, pb[0], oo);
                oo = mfma_k16(a1, pb[1], oo);
                oo = mfma_k16(a2, pb[2], oo);
                oo = mfma_k16(a3, pb[3], oo);
                if (e == 0) o0[dt] = oo; else o1[dt] = oo;
            }
        }
    }
    ls0 += __shfl_xor(ls0, 16); ls0 += __shfl_xor(ls0, 32);
    ls1 += __shfl_xor(ls1, 16); ls1 += __shfl_xor(ls1, 32);
    if (ws != 0) {
#pragma unroll
        for (int dt = 0; dt < 4; dt++)
#pragma unroll
            for (int r = 0; r < 4; r++) {
                cb[0][ws - 1][wq][lane][dt * 4 + r] = o0[dt][r];
                cb[1][ws - 1][wq][lane][dt * 4 + r] = o1[dt][r];
            }
        cb[0][ws - 1][wq][lane][16] = ls0;
        cb[1][ws - 1][wq][lane][16] = ls1;
    }
    __syncthreads();
    if (ws == 0) {
#pragma unroll
        for (int e = 0; e < 2; e++) {
            float lse = e ? ls1 : ls0;
            float lst = lse + cb[e][0][wq][lane][16] + cb[e][1][wq][lane][16]
                            + cb[e][2][wq][lane][16];
            float inv = 1.f / lst;
            uint16_t* yb = ybf + ((size_t)((b * 2 + e) * 1024 + qw)) * 512 + h * 64;
#pragma unroll
            for (int dt = 0; dt < 4; dt++) {
                uint16_t pk[4];
#pragma unroll
                for (int r = 0; r < 4; r++) {
                    float base = e ? o1[dt][r] : o0[dt][r];
                    float v = base + cb[e][0][wq][lane][dt * 4 + r]
                                   + cb[e][1][wq][lane][dt * 4 + r]
                                   + cb[e][2][wq][lane][dt * 4 + r];
                    pk[r] = f2bf(v * inv);
                }
                *(uint2*)&yb[(size_t)cl * 512 + dt * 16 + gp * 4] = *(const uint2*)pk;
            }
        }
    }
}

// 8. fused proj-GEMM + gated combine (direct store) + BCE loss (pid==32 row).
__global__ __launch_bounds__(256) void k_projc(const uint16_t* __restrict__ ybf,
                                               const uint16_t* __restrict__ Wprojt,
                                               const int* __restrict__ idx,
                                               const float* __restrict__ wsel,
                                               const float* __restrict__ gate,
                                               const float* __restrict__ x,
                                               const float* __restrict__ pl,
                                               const int* __restrict__ mask,
                                               float* __restrict__ out) {
    __shared__ uint16_t As0[64 * 40], As1[64 * 40], Bs[64 * 40];
    int pid = blockIdx.x;              // 0..32
    int tid = threadIdx.x;
    if (pid == 32) {                   // BCE loss (one block; only y==0 works)
        if (blockIdx.y != 0) return;
        __shared__ float red[4];
        int lane = tid & 63, wl = tid >> 6;
        float s = 0.f;
#pragma unroll
        for (int j = 0; j < 16; j++) {
            int i = tid * 16 + j;
            float p = pl[i];
            float tgt = (float)mask[i];
            s += fmaxf(p, 0.f) - p * tgt + log1pf(__expf(-fabsf(p)));
        }
        for (int mm = 1; mm < 64; mm <<= 1) s += __shfl_xor(s, mm);
        if (lane == 0) red[wl] = s;
        __syncthreads();
        if (tid == 0)
            out[2097152] = (red[0] + red[1] + red[2] + red[3]) * (1.0f / 4096.0f);
        return;
    }
    int b = pid >> 4, pos0 = (pid & 15) * 64;
    int n0 = blockIdx.y * 64;
    int lane = tid & 63, w = tid >> 6;
    int cl = lane & 15, gp = lane >> 4;
    f32x4 acc0[4], acc1[4];
#pragma unroll
    for (int nt = 0; nt < 4; nt++)
#pragma unroll
        for (int r = 0; r < 4; r++) { acc0[nt][r] = 0.f; acc1[nt][r] = 0.f; }
    int arow = tid >> 2, akg = tid & 3;
    const bf16x8* A8 = (const bf16x8*)ybf;
    const bf16x8* B8 = (const bf16x8*)Wprojt;
    size_t rowe0 = (size_t)(b * 2) * 1024 + pos0 + arow;
    for (int ks = 0; ks < 512; ks += 32) {
        __syncthreads();
        int kc = (ks >> 3) + akg;
        bf16x8 va0 = A8[rowe0 * 64 + kc];
        bf16x8 va1 = A8[(rowe0 + 1024) * 64 + kc];
        bf16x8 vb  = B8[(size_t)(n0 + arow) * 64 + kc];
        *(bf16x8*)&As0[arow * 40 + akg * 8] = va0;
        *(bf16x8*)&As1[arow * 40 + akg * 8] = va1;
        *(bf16x8*)&Bs[arow * 40 + akg * 8]  = vb;
        __syncthreads();
        bf16x8 a0 = *(const bf16x8*)&As0[(w * 16 + cl) * 40 + gp * 8];
        bf16x8 a1 = *(const bf16x8*)&As1[(w * 16 + cl) * 40 + gp * 8];
#pragma unroll
        for (int nt = 0; nt < 4; nt++) {
            bf16x8 bfr = *(const bf16x8*)&Bs[(nt * 16 + cl) * 40 + gp * 8];
            acc0[nt] = mfma16(a0, bfr, acc0[nt]);
            acc1[nt] = mfma16(a1, bfr, acc1[nt]);
        }
    }
#pragma unroll
    for (int r = 0; r < 4; r++) {
        int pos = pos0 + w * 16 + gp * 4 + r;
        int bk = b * 1024 + pos;
        int t = idx[bk];
        float wv = wsel[bk], g0 = gate[bk * 2], g1 = gate[bk * 2 + 1];
        const float* xrow = x + ((size_t)(b * 2048 + t)) * 512;
        float* orow = out + ((size_t)(b * 2048 + t)) * 512;
#pragma unroll
        for (int nt = 0; nt < 4; nt++) {
            int col = n0 + nt * 16 + cl;
            orow[col] = xrow[col] + wv * (g0 * acc0[nt][r] + g1 * acc1[nt][r]);
        }
    }
}

// ---------------------------------------------------------------------------
extern "C" void kernel_launch(void* const* d_in, const int* in_sizes, int n_in,
                              void* d_out, int out_size, void* d_ws, size_t ws_size,
                              hipStream_t stream) {
    const float* x        = (const float*)d_in[0];
    const float* W_router = (const float*)d_in[1];
    const float* W_q      = (const float*)d_in[2];
    const float* W_kv     = (const float*)d_in[3];
    const float* W_proj   = (const float*)d_in[4];
    const float* ln_w     = (const float*)d_in[5];
    const float* W_gate   = (const float*)d_in[6];
    const float* W_pred   = (const float*)d_in[7];

    char* ws = (char*)d_ws;
    float*    logits = (float*)   (ws + OFF_LOGITS);
    float*    pl     = (float*)   (ws + OFF_PL);
    int*      mask   = (int*)     (ws + OFF_MASK);
    int*      posmap = (int*)     (ws + OFF_POSMAP);
    int*      idx    = (int*)     (ws + OFF_IDX);
    float*    wsel   = (float*)   (ws + OFF_WSEL);
    float*    gate   = (float*)   (ws + OFF_GATE);
    uint16_t* selbf  = (uint16_t*)(ws + OFF_SELBF);
    uint16_t* Wqkvt  = (uint16_t*)(ws + OFF_WQKVT);
    uint16_t* Wprojt = (uint16_t*)(ws + OFF_WPROJT);
    float*    qkvraw = (float*)   (ws + OFF_QKVRAW);
    uint16_t* Qh     = (uint16_t*)(ws + OFF_QH);
    uint16_t* Kh     = (uint16_t*)(ws + OFF_KH);
    uint16_t* Vt     = (uint16_t*)(ws + OFF_VT);
    uint16_t* ybf    = (uint16_t*)(ws + OFF_YBF);
    float*    out    = (float*)d_out;

    k_prep       <<<1344, 256, 0, stream>>>(W_q, W_kv, W_proj, Wqkvt, Wprojt,
                                            x, W_router, W_pred, logits, pl);
    k_rank       <<<1024, 256, 0, stream>>>(logits, mask);
    k_select     <<<2, 1024, 0, stream>>>(logits, mask, idx, wsel, posmap);
    k_gather_gate<<<4096, 256, 0, stream>>>(x, idx, W_gate, posmap, selbf, gate, out);
    k_gemm       <<<dim3(16, 32), 256, 0, stream>>>(selbf, Wqkvt, qkvraw, Vt,
                                                    2048, 2048, 512);
    k_nrv        <<<2048, 256, 0, stream>>>(qkvraw, ln_w, Qh, Kh);
    k_attn       <<<512, 512, 0, stream>>>(Qh, Kh, Vt, ybf);
    k_projc      <<<dim3(33, 8), 256, 0, stream>>>(ybf, Wprojt, idx, wsel, gate, x,
                                                   pl, mask, out);
}